// Round 4
// baseline (697.119 us; speedup 1.0000x reference)
//
#include <hip/hip_runtime.h>
#include <hip/hip_fp16.h>

#define NN 100000
#define NE 1600000
#define DD 32
#define NL 3
#define NK 3
#define NB ((NN + 255) / 256)   // 391 scan blocks
#define NX 8                    // XCDs

__device__ __forceinline__ int get_xcd() {
    // s_getreg(HW_REG_XCC_ID=20, offset=0, size=32): imm = (31<<11)|(0<<6)|20
    return __builtin_amdgcn_s_getreg((31 << 11) | 20) & (NX - 1);
}

// --- per-XCD packed histogram: count in [48..], fixed-point(2^-40) wsum in [0..48).
//     Workgroup-scope atomic -> executes in XCD-local L2 (all writers of copy x are
//     on XCD x). Returned old count = local rank; pack xcd into rank[]. ---
__global__ void hist_rank_kernel(const int* __restrict__ col, const float* __restrict__ w,
                                 unsigned long long* __restrict__ pk8, int* __restrict__ rank) {
    int e = blockIdx.x * blockDim.x + threadIdx.x;
    int x = get_xcd();
    if (e < NE) {
        int c = col[e];
        unsigned long long enc = (1ull << 48) |
            (unsigned long long)((double)w[e] * 1099511627776.0);  // w * 2^40
        unsigned long long old = __hip_atomic_fetch_add(
            &pk8[(size_t)x * NN + c], enc, __ATOMIC_RELAXED, __HIP_MEMORY_SCOPE_WORKGROUP);
        rank[e] = (int)(old >> 48) | (x << 16);
    }
}

// --- reduce 8 partials: cnt, dis, and per-(node,xcd) exclusive offsets ---
__global__ void reduce_kernel(const unsigned long long* __restrict__ pk8,
                              int* __restrict__ cnt, float* __restrict__ dis,
                              int* __restrict__ off8) {
    int n = blockIdx.x * blockDim.x + threadIdx.x;
    if (n < NN) {
        int c = 0;
        unsigned long long s = 0;
        #pragma unroll
        for (int x = 0; x < NX; ++x) {
            unsigned long long p = pk8[(size_t)x * NN + n];
            off8[(size_t)x * NN + n] = c;
            c += (int)(p >> 48);
            s += (p & 0xFFFFFFFFFFFFull);
        }
        cnt[n] = c;
        float deg = (float)((double)s * (1.0 / 1099511627776.0));
        dis[n] = deg > 0.f ? rsqrtf(deg) : 0.f;
    }
}

__global__ void scan_block_kernel(const int* __restrict__ cnt, int* __restrict__ ptr,
                                  int* __restrict__ bsum) {
    __shared__ int s[256];
    int t = threadIdx.x;
    int i = blockIdx.x * 256 + t;
    int v = (i < NN) ? cnt[i] : 0;
    s[t] = v;
    __syncthreads();
    for (int off = 1; off < 256; off <<= 1) {
        int add = (t >= off) ? s[t - off] : 0;
        __syncthreads();
        s[t] += add;
        __syncthreads();
    }
    if (i < NN) ptr[i] = s[t] - v;
    if (t == 255) bsum[blockIdx.x] = s[255];
}

__global__ void scan_top_kernel(int* __restrict__ bsum, int* __restrict__ ptr) {
    __shared__ int s[512];
    int t = threadIdx.x;
    int v = (t < NB) ? bsum[t] : 0;
    s[t] = v;
    __syncthreads();
    for (int off = 1; off < 512; off <<= 1) {
        int add = (t >= off) ? s[t - off] : 0;
        __syncthreads();
        s[t] += add;
        __syncthreads();
    }
    if (t < NB) bsum[t] = s[t] - v;
    if (t == 0) ptr[NN] = NE;
}

__global__ void scan_add_kernel(int* __restrict__ ptr, const int* __restrict__ bsum) {
    int i = blockIdx.x * 256 + threadIdx.x;
    if (i < NN) ptr[i] += bsum[i >> 8];
}

// --- fill CSR (no atomics): slot = ptr[c] + off8[xcd][c] + local_rank ---
__global__ void fill_kernel(const int* __restrict__ row, const int* __restrict__ col,
                            const float* __restrict__ w, const int* __restrict__ rank,
                            const float* __restrict__ dis, const int* __restrict__ ptr,
                            const int* __restrict__ off8, int2* __restrict__ epair) {
    int e = blockIdx.x * blockDim.x + threadIdx.x;
    if (e < NE) {
        int r = row[e], c = col[e];
        int rk = rank[e];
        int x = rk >> 16, lo = rk & 0xFFFF;
        int slot = ptr[c] + off8[(size_t)x * NN + c] + lo;
        epair[slot] = make_int2(r, __float_as_int(dis[r] * w[e] * dis[c]));
    }
}

// --- convert x (fp32) -> fp16 features ---
__global__ void cvt_kernel(const float* __restrict__ x, __half* __restrict__ xh) {
    int i = blockIdx.x * blockDim.x + threadIdx.x;
    if (i < NN * DD) xh[i] = __float2half(x[i]);
}

// --- fused hop, fp16 features: agg = A-row . hin; acc=(first?hin@W0+b:acc)+agg@Wk;
//     8 edge streams x 4 lanes x 16B per 32-lane node-group. ---
__global__ __launch_bounds__(256) void hop_kernel(
    const ushort* __restrict__ hin, float* __restrict__ acc,
    ushort* __restrict__ hout, ushort* __restrict__ nxth, float* __restrict__ outf,
    const int* __restrict__ ptr, const int2* __restrict__ epair,
    const float* __restrict__ W0, const float* __restrict__ bias,
    const float* __restrict__ Wk, int first, int last) {
    __shared__ float Wks[DD * DD];
    __shared__ float W0s[DD * DD];
    int tid = threadIdx.x;
    for (int i = tid; i < DD * DD; i += 256) {
        Wks[i] = Wk[i];
        if (first) W0s[i] = W0[i];
    }
    __syncthreads();
    int lane = tid & 31;
    int st = lane >> 2;   // edge stream 0..7
    int c4 = lane & 3;    // 16B chunk of the 64B fp16 row
    int n = blockIdx.x * 8 + (tid >> 5);
    if (n >= NN) return;
    int p0 = ptr[n], p1 = ptr[n + 1];
    float agg[8] = {0.f, 0.f, 0.f, 0.f, 0.f, 0.f, 0.f, 0.f};
    const int4* hin4 = (const int4*)hin;
    for (int e0 = p0; e0 < p1; e0 += 32) {
        int m = p1 - e0;
        if (m > 32) m = 32;
        int s = 0;
        float v = 0.f;
        if (lane < m) {
            int2 ep = epair[e0 + lane];
            s = ep.x;
            v = __int_as_float(ep.y);
        }
        int nit = (m + 7) >> 3;
        for (int j = 0; j < nit; ++j) {
            int sl = j * 8 + st;
            int   ss = __shfl(s, sl, 32);   // 0 (safe) when sl >= m
            float vv = __shfl(v, sl, 32);   // 0 when sl >= m
            int4 rw = hin4[(size_t)ss * 4 + c4];
            float2 f0 = __half22float2(*reinterpret_cast<__half2*>(&rw.x));
            float2 f1 = __half22float2(*reinterpret_cast<__half2*>(&rw.y));
            float2 f2 = __half22float2(*reinterpret_cast<__half2*>(&rw.z));
            float2 f3 = __half22float2(*reinterpret_cast<__half2*>(&rw.w));
            agg[0] = fmaf(vv, f0.x, agg[0]); agg[1] = fmaf(vv, f0.y, agg[1]);
            agg[2] = fmaf(vv, f1.x, agg[2]); agg[3] = fmaf(vv, f1.y, agg[3]);
            agg[4] = fmaf(vv, f2.x, agg[4]); agg[5] = fmaf(vv, f2.y, agg[5]);
            agg[6] = fmaf(vv, f3.x, agg[6]); agg[7] = fmaf(vv, f3.y, agg[7]);
        }
    }
    // reduce the 8 streams (stream index lives in lane bits 2..4)
    #pragma unroll
    for (int i = 0; i < 8; ++i) {
        agg[i] += __shfl_xor(agg[i], 4, 32);
        agg[i] += __shfl_xor(agg[i], 8, 32);
        agg[i] += __shfl_xor(agg[i], 16, 32);
    }
    // now every lane holds dims (lane&3)*8 + i
    int idx = n * DD + lane;
    float o;
    if (first) {
        float xv = __half2float(((const __half*)hin)[idx]);
        o = bias[lane];
        #pragma unroll
        for (int i = 0; i < DD; ++i) o = fmaf(__shfl(xv, i, 32), W0s[i * DD + lane], o);
    } else {
        o = acc[idx];
    }
    #pragma unroll
    for (int c = 0; c < 4; ++c) {
        #pragma unroll
        for (int i = 0; i < 8; ++i) {
            // dim c*8+i is held by lane c (lane&3 == c there)
            o = fmaf(__shfl(agg[i], c, 32), Wks[(c * 8 + i) * DD + lane], o);
        }
    }
    if (!last) {
        if (lane < 4) {  // lane L holds chunk L's 8 dims
            __half2 ha = __floats2half2_rn(agg[0], agg[1]);
            __half2 hb = __floats2half2_rn(agg[2], agg[3]);
            __half2 hc = __floats2half2_rn(agg[4], agg[5]);
            __half2 hd = __floats2half2_rn(agg[6], agg[7]);
            int4 pkv;
            pkv.x = *(int*)&ha; pkv.y = *(int*)&hb;
            pkv.z = *(int*)&hc; pkv.w = *(int*)&hd;
            ((int4*)hout)[(size_t)n * 4 + lane] = pkv;
        }
        acc[idx] = o;
    } else {
        float r = fmaxf(o, 0.f);
        if (nxth) ((__half*)nxth)[idx] = __float2half(r);
        else outf[idx] = r;
    }
}

extern "C" void kernel_launch(void* const* d_in, const int* in_sizes, int n_in,
                              void* d_out, int out_size, void* d_ws, size_t ws_size,
                              hipStream_t stream) {
    const float* x  = (const float*)d_in[0];
    const int*   ei = (const int*)d_in[1];
    const float* ew = (const float*)d_in[2];
    const float* W  = (const float*)d_in[3];
    const float* b  = (const float*)d_in[4];
    float* out = (float*)d_out;

    const int* row = ei;        // source
    const int* col = ei + NE;   // target

    // ws layout (bytes):
    // pk8[8*N] u64 (6.4M) | epair[E] int2 (12.8M) | rank[E]/f2 (6.4M) |
    // f0 (6.4M) | f1 (6.4M) | off8[8*N] int (3.2M) | cnt | dis | ptr | bsum
    char* base = (char*)d_ws;
    unsigned long long* pk8 = (unsigned long long*)base;
    int2*   epair = (int2*)(base + 6400000);
    int*    rank  = (int*)(base + 6400000 + 12800000);     // overlaid with f2
    ushort* f2    = (ushort*)rank;                          // first written after fill
    ushort* f0    = (ushort*)(base + 25600000);
    ushort* f1    = (ushort*)(base + 32000000);
    int*    off8  = (int*)(base + 38400000);
    int*    cnt   = off8 + (size_t)NX * NN;
    float*  dis   = (float*)(cnt + NN);
    int*    ptr   = (int*)(dis + NN);
    int*    bsum  = ptr + NN + 1;

    // ---- build CSR-by-target + norms ----
    hipMemsetAsync(pk8, 0, (size_t)NX * NN * sizeof(unsigned long long), stream);
    cvt_kernel<<<(NN * DD + 255) / 256, 256, 0, stream>>>(x, (__half*)f0);
    hist_rank_kernel<<<(NE + 255) / 256, 256, 0, stream>>>(col, ew, pk8, rank);
    reduce_kernel<<<NB, 256, 0, stream>>>(pk8, cnt, dis, off8);
    scan_block_kernel<<<NB, 256, 0, stream>>>(cnt, ptr, bsum);
    scan_top_kernel<<<1, 512, 0, stream>>>(bsum, ptr);
    scan_add_kernel<<<NB, 256, 0, stream>>>(ptr, bsum);
    fill_kernel<<<(NE + 255) / 256, 256, 0, stream>>>(row, col, ew, rank, dis, ptr, off8, epair);

    // ---- layers: input always f0 (k=3 writes relu back into f0) ----
    const int grid = NN / 8;
    for (int l = 0; l < NL; ++l) {
        const float* Wl = W + (size_t)l * (NK + 1) * DD * DD;
        const float* bl = b + (size_t)l * DD;
        int lastl = (l == NL - 1);
        // k=1: acc = f0@W0 + b (+ agg@W1), gather f0 -> f1
        hop_kernel<<<grid, 256, 0, stream>>>(f0, out, f1, nullptr, nullptr,
                                             ptr, epair, Wl, bl, Wl + 1 * DD * DD, 1, 0);
        // k=2: gather f1 -> f2
        hop_kernel<<<grid, 256, 0, stream>>>(f1, out, f2, nullptr, nullptr,
                                             ptr, epair, nullptr, nullptr, Wl + 2 * DD * DD, 0, 0);
        // k=3: gather f2, relu -> f0 (or fp32 out on the last layer)
        hop_kernel<<<grid, 256, 0, stream>>>(f2, out, nullptr,
                                             lastl ? nullptr : f0, lastl ? out : nullptr,
                                             ptr, epair, nullptr, nullptr, Wl + 3 * DD * DD, 0, 1);
    }
}

// Round 5
// 694.863 us; speedup vs baseline: 1.0032x; 1.0032x over previous
//
#include <hip/hip_runtime.h>
#include <hip/hip_fp16.h>

#define NN 100000
#define NE 1600000
#define DD 32
#define NL 3
#define NK 3
#define NB ((NN + 255) / 256)   // 391 scan blocks
#define NX 8                    // XCDs

__device__ __forceinline__ int get_xcd() {
    return __builtin_amdgcn_s_getreg((31 << 11) | 20) & (NX - 1);
}

// --- per-XCD packed histogram (XCD-local L2 atomics): count [48..], fp(2^-40) wsum [0..48) ---
__global__ void hist_rank_kernel(const int* __restrict__ col, const float* __restrict__ w,
                                 unsigned long long* __restrict__ pk8, int* __restrict__ rank) {
    int e = blockIdx.x * blockDim.x + threadIdx.x;
    int x = get_xcd();
    if (e < NE) {
        int c = col[e];
        unsigned long long enc = (1ull << 48) |
            (unsigned long long)((double)w[e] * 1099511627776.0);  // w * 2^40
        unsigned long long old = __hip_atomic_fetch_add(
            &pk8[(size_t)x * NN + c], enc, __ATOMIC_RELAXED, __HIP_MEMORY_SCOPE_WORKGROUP);
        rank[e] = (int)(old >> 48) | (x << 16);
    }
}

// --- reduce 8 partials: cnt, dis, per-(node,xcd) exclusive offsets ---
__global__ void reduce_kernel(const unsigned long long* __restrict__ pk8,
                              int* __restrict__ cnt, float* __restrict__ dis,
                              int* __restrict__ off8) {
    int n = blockIdx.x * blockDim.x + threadIdx.x;
    if (n < NN) {
        int c = 0;
        unsigned long long s = 0;
        #pragma unroll
        for (int x = 0; x < NX; ++x) {
            unsigned long long p = pk8[(size_t)x * NN + n];
            off8[(size_t)x * NN + n] = c;
            c += (int)(p >> 48);
            s += (p & 0xFFFFFFFFFFFFull);
        }
        cnt[n] = c;
        float deg = (float)((double)s * (1.0 / 1099511627776.0));
        dis[n] = deg > 0.f ? rsqrtf(deg) : 0.f;
    }
}

__global__ void scan_block_kernel(const int* __restrict__ cnt, int* __restrict__ ptr,
                                  int* __restrict__ bsum) {
    __shared__ int s[256];
    int t = threadIdx.x;
    int i = blockIdx.x * 256 + t;
    int v = (i < NN) ? cnt[i] : 0;
    s[t] = v;
    __syncthreads();
    for (int off = 1; off < 256; off <<= 1) {
        int add = (t >= off) ? s[t - off] : 0;
        __syncthreads();
        s[t] += add;
        __syncthreads();
    }
    if (i < NN) ptr[i] = s[t] - v;
    if (t == 255) bsum[blockIdx.x] = s[255];
}

__global__ void scan_top_kernel(int* __restrict__ bsum, int* __restrict__ ptr) {
    __shared__ int s[512];
    int t = threadIdx.x;
    int v = (t < NB) ? bsum[t] : 0;
    s[t] = v;
    __syncthreads();
    for (int off = 1; off < 512; off <<= 1) {
        int add = (t >= off) ? s[t - off] : 0;
        __syncthreads();
        s[t] += add;
        __syncthreads();
    }
    if (t < NB) bsum[t] = s[t] - v;
    if (t == 0) ptr[NN] = NE;
}

__global__ void scan_add_kernel(int* __restrict__ ptr, const int* __restrict__ bsum) {
    int i = blockIdx.x * 256 + threadIdx.x;
    if (i < NN) ptr[i] += bsum[i >> 8];
}

// --- fill CSR (no atomics) ---
__global__ void fill_kernel(const int* __restrict__ row, const int* __restrict__ col,
                            const float* __restrict__ w, const int* __restrict__ rank,
                            const float* __restrict__ dis, const int* __restrict__ ptr,
                            const int* __restrict__ off8, int2* __restrict__ epair) {
    int e = blockIdx.x * blockDim.x + threadIdx.x;
    if (e < NE) {
        int r = row[e], c = col[e];
        int rk = rank[e];
        int x = rk >> 16, lo = rk & 0xFFFF;
        int slot = ptr[c] + off8[(size_t)x * NN + c] + lo;
        epair[slot] = make_int2(r, __float_as_int(dis[r] * w[e] * dis[c]));
    }
}

__global__ void cvt_kernel(const float* __restrict__ x, __half* __restrict__ xh) {
    int i = blockIdx.x * blockDim.x + threadIdx.x;
    if (i < NN * DD) xh[i] = __float2half(x[i]);
}

// ---- shared gather body: agg[8] per lane, dims (lane&3)*8+i, replicated over streams ----
__device__ __forceinline__ void gather_body(const ushort* __restrict__ hin,
                                            const int2* __restrict__ epair,
                                            int p0, int p1, int lane, int st, int c4,
                                            float agg[8]) {
    const int4* hin4 = (const int4*)hin;
    for (int e0 = p0; e0 < p1; e0 += 32) {
        int m = p1 - e0;
        if (m > 32) m = 32;
        int s = 0;
        float v = 0.f;
        if (lane < m) {
            long long ep = __builtin_nontemporal_load((const long long*)epair + e0 + lane);
            s = (int)(ep & 0xFFFFFFFFll);
            v = __int_as_float((int)(ep >> 32));
        }
        int nit = (m + 7) >> 3;
        #pragma unroll 2
        for (int j = 0; j < nit; ++j) {
            int sl = j * 8 + st;
            int   ss = __shfl(s, sl, 32);   // 0 (safe) when sl >= m
            float vv = __shfl(v, sl, 32);   // 0 when sl >= m
            int4 rw = hin4[(size_t)ss * 4 + c4];
            float2 f0 = __half22float2(*reinterpret_cast<__half2*>(&rw.x));
            float2 f1 = __half22float2(*reinterpret_cast<__half2*>(&rw.y));
            float2 f2 = __half22float2(*reinterpret_cast<__half2*>(&rw.z));
            float2 f3 = __half22float2(*reinterpret_cast<__half2*>(&rw.w));
            agg[0] = fmaf(vv, f0.x, agg[0]); agg[1] = fmaf(vv, f0.y, agg[1]);
            agg[2] = fmaf(vv, f1.x, agg[2]); agg[3] = fmaf(vv, f1.y, agg[3]);
            agg[4] = fmaf(vv, f2.x, agg[4]); agg[5] = fmaf(vv, f2.y, agg[5]);
            agg[6] = fmaf(vv, f3.x, agg[6]); agg[7] = fmaf(vv, f3.y, agg[7]);
        }
    }
    #pragma unroll
    for (int i = 0; i < 8; ++i) {
        agg[i] += __shfl_xor(agg[i], 4, 32);
        agg[i] += __shfl_xor(agg[i], 8, 32);
        agg[i] += __shfl_xor(agg[i], 16, 32);
    }
}

// --- pure hop: hout[n] = sum val*hin[src], fp16 in/out ---
__global__ __launch_bounds__(256) void gather_kernel(
    const ushort* __restrict__ hin, ushort* __restrict__ hout,
    const int* __restrict__ ptr, const int2* __restrict__ epair) {
    int tid = threadIdx.x;
    int lane = tid & 31;
    int st = lane >> 2, c4 = lane & 3;
    int n = blockIdx.x * 8 + (tid >> 5);
    if (n >= NN) return;
    int p0 = ptr[n], p1 = ptr[n + 1];
    float agg[8] = {0.f, 0.f, 0.f, 0.f, 0.f, 0.f, 0.f, 0.f};
    gather_body(hin, epair, p0, p1, lane, st, c4, agg);
    if (lane < 4) {
        __half2 ha = __floats2half2_rn(agg[0], agg[1]);
        __half2 hb = __floats2half2_rn(agg[2], agg[3]);
        __half2 hc = __floats2half2_rn(agg[4], agg[5]);
        __half2 hd = __floats2half2_rn(agg[6], agg[7]);
        int4 pkv;
        pkv.x = *(int*)&ha; pkv.y = *(int*)&hb;
        pkv.z = *(int*)&hc; pkv.w = *(int*)&hd;
        ((int4*)hout)[(size_t)n * 4 + lane] = pkv;
    }
}

// --- layer end: gather h2 -> agg3; o = b + f0@W0 + h1@W1 + h2@W2 + agg3@W3; relu ->
//     fp16 f0 (in place) or fp32 out on the last layer. No global acc ever. ---
__global__ __launch_bounds__(256) void layer_end_kernel(
    const ushort* __restrict__ f0, const ushort* __restrict__ h1,
    const ushort* __restrict__ h2, ushort* __restrict__ f0out,
    float* __restrict__ outf,
    const int* __restrict__ ptr, const int2* __restrict__ epair,
    const float* __restrict__ Wl, const float* __restrict__ bias, int last) {
    __shared__ float Ws[4][DD * DD];
    __shared__ float bs[DD];
    int tid = threadIdx.x;
    for (int i = tid; i < 4 * DD * DD; i += 256) Ws[i >> 10][i & 1023] = Wl[i];
    if (tid < DD) bs[tid] = bias[tid];
    __syncthreads();
    int lane = tid & 31;
    int st = lane >> 2, c4 = lane & 3;
    int n = blockIdx.x * 8 + (tid >> 5);
    if (n >= NN) return;
    int p0 = ptr[n], p1 = ptr[n + 1];
    float agg[8] = {0.f, 0.f, 0.f, 0.f, 0.f, 0.f, 0.f, 0.f};
    gather_body(h2, epair, p0, p1, lane, st, c4, agg);

    int idx = n * DD + lane;
    float o = bs[lane];
    float xv = __half2float(((const __half*)f0)[idx]);
    float a1 = __half2float(((const __half*)h1)[idx]);
    float a2 = __half2float(((const __half*)h2)[idx]);
    #pragma unroll
    for (int i = 0; i < DD; ++i) {
        o = fmaf(__shfl(xv, i, 32), Ws[0][i * DD + lane], o);
        o = fmaf(__shfl(a1, i, 32), Ws[1][i * DD + lane], o);
        o = fmaf(__shfl(a2, i, 32), Ws[2][i * DD + lane], o);
    }
    #pragma unroll
    for (int c = 0; c < 4; ++c) {
        #pragma unroll
        for (int i = 0; i < 8; ++i) {
            o = fmaf(__shfl(agg[i], c, 32), Ws[3][(c * 8 + i) * DD + lane], o);
        }
    }
    float r = fmaxf(o, 0.f);
    if (last) outf[idx] = r;
    else ((__half*)f0out)[idx] = __float2half(r);
}

extern "C" void kernel_launch(void* const* d_in, const int* in_sizes, int n_in,
                              void* d_out, int out_size, void* d_ws, size_t ws_size,
                              hipStream_t stream) {
    const float* x  = (const float*)d_in[0];
    const int*   ei = (const int*)d_in[1];
    const float* ew = (const float*)d_in[2];
    const float* W  = (const float*)d_in[3];
    const float* b  = (const float*)d_in[4];
    float* out = (float*)d_out;

    const int* row = ei;        // source
    const int* col = ei + NE;   // target

    // ws layout (bytes): pk8 6.4M | epair 12.8M | rank/f1 6.4M | f0 6.4M | f2 6.4M |
    //                    off8 3.2M | cnt | dis | ptr | bsum     (~42.8 MB total)
    char* base = (char*)d_ws;
    unsigned long long* pk8 = (unsigned long long*)base;
    int2*   epair = (int2*)(base + 6400000);
    int*    rank  = (int*)(base + 6400000 + 12800000);   // overlaid with f1
    ushort* f1    = (ushort*)rank;                        // first written after fill
    ushort* f0    = (ushort*)(base + 25600000);
    ushort* f2    = (ushort*)(base + 32000000);
    int*    off8  = (int*)(base + 38400000);
    int*    cnt   = off8 + (size_t)NX * NN;
    float*  dis   = (float*)(cnt + NN);
    int*    ptr   = (int*)(dis + NN);
    int*    bsum  = ptr + NN + 1;

    // ---- build CSR-by-target + norms ----
    hipMemsetAsync(pk8, 0, (size_t)NX * NN * sizeof(unsigned long long), stream);
    cvt_kernel<<<(NN * DD + 255) / 256, 256, 0, stream>>>(x, (__half*)f0);
    hist_rank_kernel<<<(NE + 255) / 256, 256, 0, stream>>>(col, ew, pk8, rank);
    reduce_kernel<<<NB, 256, 0, stream>>>(pk8, cnt, dis, off8);
    scan_block_kernel<<<NB, 256, 0, stream>>>(cnt, ptr, bsum);
    scan_top_kernel<<<1, 512, 0, stream>>>(bsum, ptr);
    scan_add_kernel<<<NB, 256, 0, stream>>>(ptr, bsum);
    fill_kernel<<<(NE + 255) / 256, 256, 0, stream>>>(row, col, ew, rank, dis, ptr, off8, epair);

    // ---- layers: f0 = layer input (fp16, updated in place each layer) ----
    const int grid = NN / 8;
    for (int l = 0; l < NL; ++l) {
        const float* Wl = W + (size_t)l * (NK + 1) * DD * DD;
        const float* bl = b + (size_t)l * DD;
        int lastl = (l == NL - 1);
        gather_kernel<<<grid, 256, 0, stream>>>(f0, f1, ptr, epair);          // k=1
        gather_kernel<<<grid, 256, 0, stream>>>(f1, f2, ptr, epair);          // k=2
        layer_end_kernel<<<grid, 256, 0, stream>>>(f0, f1, f2, f0, out,       // k=3 + epilogue
                                                   ptr, epair, Wl, bl, lastl);
    }
}

// Round 6
// 462.462 us; speedup vs baseline: 1.5074x; 1.5025x over previous
//
#include <hip/hip_runtime.h>
#include <hip/hip_fp16.h>

#define NN 100000
#define NE 1600000
#define DD 32
#define NL 3
#define NK 3
#define NB ((NN + 255) / 256)   // 391 scan blocks
#define NX 8                    // XCDs
#define NTILE (NN / 16)         // 6250 MFMA node tiles

typedef _Float16 half8 __attribute__((ext_vector_type(8)));
typedef float f32x4 __attribute__((ext_vector_type(4)));

__device__ __forceinline__ int get_xcd() {
    return __builtin_amdgcn_s_getreg((31 << 11) | 20) & (NX - 1);
}

// --- per-XCD packed histogram (XCD-local L2 atomics): count [48..], fp(2^-40) wsum [0..48) ---
__global__ void hist_rank_kernel(const int* __restrict__ col, const float* __restrict__ w,
                                 unsigned long long* __restrict__ pk8, int* __restrict__ rank) {
    int e = blockIdx.x * blockDim.x + threadIdx.x;
    int x = get_xcd();
    if (e < NE) {
        int c = col[e];
        unsigned long long enc = (1ull << 48) |
            (unsigned long long)((double)w[e] * 1099511627776.0);  // w * 2^40
        unsigned long long old = __hip_atomic_fetch_add(
            &pk8[(size_t)x * NN + c], enc, __ATOMIC_RELAXED, __HIP_MEMORY_SCOPE_WORKGROUP);
        rank[e] = (int)(old >> 48) | (x << 16);
    }
}

// --- reduce 8 partials: cnt, dis, per-(node,xcd) exclusive offsets ---
__global__ void reduce_kernel(const unsigned long long* __restrict__ pk8,
                              int* __restrict__ cnt, float* __restrict__ dis,
                              int* __restrict__ off8) {
    int n = blockIdx.x * blockDim.x + threadIdx.x;
    if (n < NN) {
        int c = 0;
        unsigned long long s = 0;
        #pragma unroll
        for (int x = 0; x < NX; ++x) {
            unsigned long long p = pk8[(size_t)x * NN + n];
            off8[(size_t)x * NN + n] = c;
            c += (int)(p >> 48);
            s += (p & 0xFFFFFFFFFFFFull);
        }
        cnt[n] = c;
        float deg = (float)((double)s * (1.0 / 1099511627776.0));
        dis[n] = deg > 0.f ? rsqrtf(deg) : 0.f;
    }
}

__global__ void scan_block_kernel(const int* __restrict__ cnt, int* __restrict__ ptr,
                                  int* __restrict__ bsum) {
    __shared__ int s[256];
    int t = threadIdx.x;
    int i = blockIdx.x * 256 + t;
    int v = (i < NN) ? cnt[i] : 0;
    s[t] = v;
    __syncthreads();
    for (int off = 1; off < 256; off <<= 1) {
        int add = (t >= off) ? s[t - off] : 0;
        __syncthreads();
        s[t] += add;
        __syncthreads();
    }
    if (i < NN) ptr[i] = s[t] - v;
    if (t == 255) bsum[blockIdx.x] = s[255];
}

__global__ void scan_top_kernel(int* __restrict__ bsum, int* __restrict__ ptr) {
    __shared__ int s[512];
    int t = threadIdx.x;
    int v = (t < NB) ? bsum[t] : 0;
    s[t] = v;
    __syncthreads();
    for (int off = 1; off < 512; off <<= 1) {
        int add = (t >= off) ? s[t - off] : 0;
        __syncthreads();
        s[t] += add;
        __syncthreads();
    }
    if (t < NB) bsum[t] = s[t] - v;
    if (t == 0) ptr[NN] = NE;
}

__global__ void scan_add_kernel(int* __restrict__ ptr, const int* __restrict__ bsum) {
    int i = blockIdx.x * 256 + threadIdx.x;
    if (i < NN) ptr[i] += bsum[i >> 8];
}

// --- fill CSR (no atomics) ---
__global__ void fill_kernel(const int* __restrict__ row, const int* __restrict__ col,
                            const float* __restrict__ w, const int* __restrict__ rank,
                            const float* __restrict__ dis, const int* __restrict__ ptr,
                            const int* __restrict__ off8, int2* __restrict__ epair) {
    int e = blockIdx.x * blockDim.x + threadIdx.x;
    if (e < NE) {
        int r = row[e], c = col[e];
        int rk = rank[e];
        int x = rk >> 16, lo = rk & 0xFFFF;
        int slot = ptr[c] + off8[(size_t)x * NN + c] + lo;
        epair[slot] = make_int2(r, __float_as_int(dis[r] * w[e] * dis[c]));
    }
}

__global__ void cvt_kernel(const float* __restrict__ x, __half* __restrict__ xh) {
    int i = blockIdx.x * blockDim.x + threadIdx.x;
    if (i < NN * DD) xh[i] = __float2half(x[i]);
}

// --- pure hop: hout[n] = sum val*hin[src], fp16 in/out.
//     8 edge streams x 4 lanes x 16B per 32-lane node-group. ---
__global__ __launch_bounds__(256) void gather_kernel(
    const ushort* __restrict__ hin, ushort* __restrict__ hout,
    const int* __restrict__ ptr, const int2* __restrict__ epair) {
    int tid = threadIdx.x;
    int lane = tid & 31;
    int st = lane >> 2, c4 = lane & 3;
    int n = blockIdx.x * 8 + (tid >> 5);
    if (n >= NN) return;
    int p0 = ptr[n], p1 = ptr[n + 1];
    float agg[8] = {0.f, 0.f, 0.f, 0.f, 0.f, 0.f, 0.f, 0.f};
    const int4* hin4 = (const int4*)hin;
    for (int e0 = p0; e0 < p1; e0 += 32) {
        int m = p1 - e0;
        if (m > 32) m = 32;
        int s = 0;
        float v = 0.f;
        if (lane < m) {
            long long ep = __builtin_nontemporal_load((const long long*)epair + e0 + lane);
            s = (int)(ep & 0xFFFFFFFFll);
            v = __int_as_float((int)(ep >> 32));
        }
        int nit = (m + 7) >> 3;
        #pragma unroll 2
        for (int j = 0; j < nit; ++j) {
            int sl = j * 8 + st;
            int   ss = __shfl(s, sl, 32);   // 0 (safe) when sl >= m
            float vv = __shfl(v, sl, 32);   // 0 when sl >= m
            int4 rw = hin4[(size_t)ss * 4 + c4];
            float2 f0 = __half22float2(*reinterpret_cast<__half2*>(&rw.x));
            float2 f1 = __half22float2(*reinterpret_cast<__half2*>(&rw.y));
            float2 f2 = __half22float2(*reinterpret_cast<__half2*>(&rw.z));
            float2 f3 = __half22float2(*reinterpret_cast<__half2*>(&rw.w));
            agg[0] = fmaf(vv, f0.x, agg[0]); agg[1] = fmaf(vv, f0.y, agg[1]);
            agg[2] = fmaf(vv, f1.x, agg[2]); agg[3] = fmaf(vv, f1.y, agg[3]);
            agg[4] = fmaf(vv, f2.x, agg[4]); agg[5] = fmaf(vv, f2.y, agg[5]);
            agg[6] = fmaf(vv, f3.x, agg[6]); agg[7] = fmaf(vv, f3.y, agg[7]);
        }
    }
    #pragma unroll
    for (int i = 0; i < 8; ++i) {
        agg[i] += __shfl_xor(agg[i], 4, 32);
        agg[i] += __shfl_xor(agg[i], 8, 32);
        agg[i] += __shfl_xor(agg[i], 16, 32);
    }
    if (lane < 4) {
        __half2 ha = __floats2half2_rn(agg[0], agg[1]);
        __half2 hb = __floats2half2_rn(agg[2], agg[3]);
        __half2 hc = __floats2half2_rn(agg[4], agg[5]);
        __half2 hd = __floats2half2_rn(agg[6], agg[7]);
        int4 pkv;
        pkv.x = *(int*)&ha; pkv.y = *(int*)&hb;
        pkv.z = *(int*)&hc; pkv.w = *(int*)&hd;
        ((int4*)hout)[(size_t)n * 4 + lane] = pkv;
    }
}

// --- MFMA epilogue: o = b + [f0|h1|h2|h3] @ [W0;W1;W2;W3]; relu; -> fp16 f0 or fp32 out.
//     One wave per 16-node tile (grid-stride). W split hi+lo fp16 so W error ~2^-21.
//     A-frag: lane holds row (lane&15), k = (lane>>4)*8..+7 -> one contiguous half8. ---
__global__ __launch_bounds__(256) void epilogue_kernel(
    const ushort* __restrict__ f0, const ushort* __restrict__ h1,
    const ushort* __restrict__ h2, const ushort* __restrict__ h3,
    ushort* __restrict__ f0out, float* __restrict__ outf,
    const float* __restrict__ Wl, const float* __restrict__ bias, int last) {
    int tid = threadIdx.x;
    int lane = tid & 63;
    int wv = tid >> 6;
    int m = lane & 15;
    int kq = lane >> 4;   // 0..3
    // B-frag prep (once per wave): lane holds B[kq*8+j][n=m (+16)], hi/lo split
    half8 Bhi[4][2], Blo[4][2];
    #pragma unroll
    for (int c = 0; c < 4; ++c) {
        #pragma unroll
        for (int h = 0; h < 2; ++h) {
            #pragma unroll
            for (int j = 0; j < 8; ++j) {
                float w = Wl[c * 1024 + (kq * 8 + j) * 32 + h * 16 + m];
                _Float16 hi = (_Float16)w;
                Bhi[c][h][j] = hi;
                Blo[c][h][j] = (_Float16)(w - (float)hi);
            }
        }
    }
    float b0 = bias[m], b1 = bias[16 + m];
    const half8* A0 = (const half8*)f0;
    const half8* A1 = (const half8*)h1;
    const half8* A2 = (const half8*)h2;
    const half8* A3 = (const half8*)h3;
    int wgid = blockIdx.x * 4 + wv;
    for (int t = wgid; t < NTILE; t += 391 * 4) {
        int n0 = t * 16;
        int ai = (n0 + m) * 4 + kq;
        f32x4 acc0 = {0.f, 0.f, 0.f, 0.f};
        f32x4 acc1 = {0.f, 0.f, 0.f, 0.f};
        half8 a;
        a = A0[ai];
        acc0 = __builtin_amdgcn_mfma_f32_16x16x32_f16(a, Bhi[0][0], acc0, 0, 0, 0);
        acc0 = __builtin_amdgcn_mfma_f32_16x16x32_f16(a, Blo[0][0], acc0, 0, 0, 0);
        acc1 = __builtin_amdgcn_mfma_f32_16x16x32_f16(a, Bhi[0][1], acc1, 0, 0, 0);
        acc1 = __builtin_amdgcn_mfma_f32_16x16x32_f16(a, Blo[0][1], acc1, 0, 0, 0);
        a = A1[ai];
        acc0 = __builtin_amdgcn_mfma_f32_16x16x32_f16(a, Bhi[1][0], acc0, 0, 0, 0);
        acc0 = __builtin_amdgcn_mfma_f32_16x16x32_f16(a, Blo[1][0], acc0, 0, 0, 0);
        acc1 = __builtin_amdgcn_mfma_f32_16x16x32_f16(a, Bhi[1][1], acc1, 0, 0, 0);
        acc1 = __builtin_amdgcn_mfma_f32_16x16x32_f16(a, Blo[1][1], acc1, 0, 0, 0);
        a = A2[ai];
        acc0 = __builtin_amdgcn_mfma_f32_16x16x32_f16(a, Bhi[2][0], acc0, 0, 0, 0);
        acc0 = __builtin_amdgcn_mfma_f32_16x16x32_f16(a, Blo[2][0], acc0, 0, 0, 0);
        acc1 = __builtin_amdgcn_mfma_f32_16x16x32_f16(a, Bhi[2][1], acc1, 0, 0, 0);
        acc1 = __builtin_amdgcn_mfma_f32_16x16x32_f16(a, Blo[2][1], acc1, 0, 0, 0);
        a = A3[ai];
        acc0 = __builtin_amdgcn_mfma_f32_16x16x32_f16(a, Bhi[3][0], acc0, 0, 0, 0);
        acc0 = __builtin_amdgcn_mfma_f32_16x16x32_f16(a, Blo[3][0], acc0, 0, 0, 0);
        acc1 = __builtin_amdgcn_mfma_f32_16x16x32_f16(a, Bhi[3][1], acc1, 0, 0, 0);
        acc1 = __builtin_amdgcn_mfma_f32_16x16x32_f16(a, Blo[3][1], acc1, 0, 0, 0);
        // C/D: col = lane&15 (+16 for acc1), row = n0 + kq*4 + r
        #pragma unroll
        for (int r = 0; r < 4; ++r) {
            int rowi = n0 + kq * 4 + r;
            float v0 = fmaxf(acc0[r] + b0, 0.f);
            float v1 = fmaxf(acc1[r] + b1, 0.f);
            if (last) {
                outf[rowi * DD + m] = v0;
                outf[rowi * DD + 16 + m] = v1;
            } else {
                ((__half*)f0out)[rowi * DD + m] = __float2half(v0);
                ((__half*)f0out)[rowi * DD + 16 + m] = __float2half(v1);
            }
        }
    }
}

extern "C" void kernel_launch(void* const* d_in, const int* in_sizes, int n_in,
                              void* d_out, int out_size, void* d_ws, size_t ws_size,
                              hipStream_t stream) {
    const float* x  = (const float*)d_in[0];
    const int*   ei = (const int*)d_in[1];
    const float* ew = (const float*)d_in[2];
    const float* W  = (const float*)d_in[3];
    const float* b  = (const float*)d_in[4];
    float* out = (float*)d_out;

    const int* row = ei;        // source
    const int* col = ei + NE;   // target

    // ws layout (bytes): pk8/h3 6.4M | epair 12.8M | rank/h1 6.4M | f0 6.4M | h2 6.4M |
    //                    off8 3.2M | cnt | dis | ptr | bsum     (~42.8 MB total)
    char* base = (char*)d_ws;
    unsigned long long* pk8 = (unsigned long long*)base;
    ushort* h3    = (ushort*)base;                        // overlaid: pk8 dead after reduce
    int2*   epair = (int2*)(base + 6400000);
    int*    rank  = (int*)(base + 6400000 + 12800000);    // overlaid with h1
    ushort* h1    = (ushort*)rank;                        // first written after fill
    ushort* f0    = (ushort*)(base + 25600000);
    ushort* h2    = (ushort*)(base + 32000000);
    int*    off8  = (int*)(base + 38400000);
    int*    cnt   = off8 + (size_t)NX * NN;
    float*  dis   = (float*)(cnt + NN);
    int*    ptr   = (int*)(dis + NN);
    int*    bsum  = ptr + NN + 1;

    // ---- build CSR-by-target + norms ----
    hipMemsetAsync(pk8, 0, (size_t)NX * NN * sizeof(unsigned long long), stream);
    cvt_kernel<<<(NN * DD + 255) / 256, 256, 0, stream>>>(x, (__half*)f0);
    hist_rank_kernel<<<(NE + 255) / 256, 256, 0, stream>>>(col, ew, pk8, rank);
    reduce_kernel<<<NB, 256, 0, stream>>>(pk8, cnt, dis, off8);
    scan_block_kernel<<<NB, 256, 0, stream>>>(cnt, ptr, bsum);
    scan_top_kernel<<<1, 512, 0, stream>>>(bsum, ptr);
    scan_add_kernel<<<NB, 256, 0, stream>>>(ptr, bsum);
    fill_kernel<<<(NE + 255) / 256, 256, 0, stream>>>(row, col, ew, rank, dis, ptr, off8, epair);

    // ---- layers: f0 = layer input (fp16, updated in place by epilogue) ----
    const int grid = NN / 8;
    for (int l = 0; l < NL; ++l) {
        const float* Wl = W + (size_t)l * (NK + 1) * DD * DD;
        const float* bl = b + (size_t)l * DD;
        int lastl = (l == NL - 1);
        gather_kernel<<<grid, 256, 0, stream>>>(f0, h1, ptr, epair);   // k=1
        gather_kernel<<<grid, 256, 0, stream>>>(h1, h2, ptr, epair);   // k=2
        gather_kernel<<<grid, 256, 0, stream>>>(h2, h3, ptr, epair);   // k=3
        epilogue_kernel<<<391, 256, 0, stream>>>(f0, h1, h2, h3, f0, out,
                                                 Wl, bl, lastl);
    }
}

// Round 8
// 460.045 us; speedup vs baseline: 1.5153x; 1.0053x over previous
//
#include <hip/hip_runtime.h>
#include <hip/hip_fp16.h>

#define NN 100000
#define NE 1600000
#define DD 32
#define NL 3
#define NK 3
#define NB ((NN + 255) / 256)   // 391 scan blocks
#define NX 8                    // XCDs
#define NTILE (NN / 16)         // 6250 MFMA node tiles

typedef _Float16 half8 __attribute__((ext_vector_type(8)));
typedef float f32x4 __attribute__((ext_vector_type(4)));

__device__ __forceinline__ int get_xcd() {
    return __builtin_amdgcn_s_getreg((31 << 11) | 20) & (NX - 1);
}

// --- per-XCD packed histogram (XCD-local L2 atomics): count [48..], fp(2^-40) wsum [0..48) ---
__global__ void hist_rank_kernel(const int* __restrict__ col, const float* __restrict__ w,
                                 unsigned long long* __restrict__ pk8, int* __restrict__ rank) {
    int e = blockIdx.x * blockDim.x + threadIdx.x;
    int x = get_xcd();
    if (e < NE) {
        int c = col[e];
        unsigned long long enc = (1ull << 48) |
            (unsigned long long)((double)w[e] * 1099511627776.0);  // w * 2^40
        unsigned long long old = __hip_atomic_fetch_add(
            &pk8[(size_t)x * NN + c], enc, __ATOMIC_RELAXED, __HIP_MEMORY_SCOPE_WORKGROUP);
        rank[e] = (int)(old >> 48) | (x << 16);
    }
}

// --- reduce 8 partials: cnt, dis, per-(node,xcd) exclusive offsets ---
__global__ void reduce_kernel(const unsigned long long* __restrict__ pk8,
                              int* __restrict__ cnt, float* __restrict__ dis,
                              int* __restrict__ off8) {
    int n = blockIdx.x * blockDim.x + threadIdx.x;
    if (n < NN) {
        int c = 0;
        unsigned long long s = 0;
        #pragma unroll
        for (int x = 0; x < NX; ++x) {
            unsigned long long p = pk8[(size_t)x * NN + n];
            off8[(size_t)x * NN + n] = c;
            c += (int)(p >> 48);
            s += (p & 0xFFFFFFFFFFFFull);
        }
        cnt[n] = c;
        float deg = (float)((double)s * (1.0 / 1099511627776.0));
        dis[n] = deg > 0.f ? rsqrtf(deg) : 0.f;
    }
}

__global__ void scan_block_kernel(const int* __restrict__ cnt, int* __restrict__ ptr,
                                  int* __restrict__ bsum) {
    __shared__ int s[256];
    int t = threadIdx.x;
    int i = blockIdx.x * 256 + t;
    int v = (i < NN) ? cnt[i] : 0;
    s[t] = v;
    __syncthreads();
    for (int off = 1; off < 256; off <<= 1) {
        int add = (t >= off) ? s[t - off] : 0;
        __syncthreads();
        s[t] += add;
        __syncthreads();
    }
    if (i < NN) ptr[i] = s[t] - v;
    if (t == 255) bsum[blockIdx.x] = s[255];
}

__global__ void scan_top_kernel(int* __restrict__ bsum, int* __restrict__ ptr) {
    __shared__ int s[512];
    int t = threadIdx.x;
    int v = (t < NB) ? bsum[t] : 0;
    s[t] = v;
    __syncthreads();
    for (int off = 1; off < 512; off <<= 1) {
        int add = (t >= off) ? s[t - off] : 0;
        __syncthreads();
        s[t] += add;
        __syncthreads();
    }
    if (t < NB) bsum[t] = s[t] - v;
    if (t == 0) ptr[NN] = NE;
}

__global__ void scan_add_kernel(int* __restrict__ ptr, const int* __restrict__ bsum) {
    int i = blockIdx.x * 256 + threadIdx.x;
    if (i < NN) ptr[i] += bsum[i >> 8];
}

// --- fill CSR (no atomics): epair = (fp16_bits(norm) << 17) | src.
//     norm >= 0 so its fp16 pattern has bit15==0 -> fits in 15 bits exactly. ---
__global__ void fill_kernel(const int* __restrict__ row, const int* __restrict__ col,
                            const float* __restrict__ w, const int* __restrict__ rank,
                            const float* __restrict__ dis, const int* __restrict__ ptr,
                            const int* __restrict__ off8, unsigned* __restrict__ epair) {
    int e = blockIdx.x * blockDim.x + threadIdx.x;
    if (e < NE) {
        int r = row[e], c = col[e];
        int rk = rank[e];
        int x = rk >> 16, lo = rk & 0xFFFF;
        int slot = ptr[c] + off8[(size_t)x * NN + c] + lo;
        float nv = dis[r] * w[e] * dis[c];
        unsigned hb = (unsigned)__half_as_ushort(__float2half(nv));
        epair[slot] = (hb << 17) | (unsigned)r;
    }
}

__global__ void cvt_kernel(const float* __restrict__ x, __half* __restrict__ xh) {
    int i = blockIdx.x * blockDim.x + threadIdx.x;
    if (i < NN * DD) xh[i] = __float2half(x[i]);
}

// --- pure hop: hout[n] = sum norm*hin[src], fp16 in/out; 4B packed edges.
//     8 edge streams x 4 lanes x 16B per 32-lane node-group. ---
__global__ __launch_bounds__(256) void gather_kernel(
    const ushort* __restrict__ hin, ushort* __restrict__ hout,
    const int* __restrict__ ptr, const unsigned* __restrict__ epair) {
    int tid = threadIdx.x;
    int lane = tid & 31;
    int st = lane >> 2, c4 = lane & 3;
    int n = blockIdx.x * 8 + (tid >> 5);
    if (n >= NN) return;
    int p0 = ptr[n], p1 = ptr[n + 1];
    float agg[8] = {0.f, 0.f, 0.f, 0.f, 0.f, 0.f, 0.f, 0.f};
    const int4* hin4 = (const int4*)hin;
    for (int e0 = p0; e0 < p1; e0 += 32) {
        int m = p1 - e0;
        if (m > 32) m = 32;
        int s = 0;
        float v = 0.f;
        if (lane < m) {
            unsigned p = __builtin_nontemporal_load(epair + e0 + lane);
            s = (int)(p & 0x1FFFFu);
            v = __half2float(__ushort_as_half((unsigned short)(p >> 17)));
        }
        int nit = (m + 7) >> 3;
        #pragma unroll 2
        for (int j = 0; j < nit; ++j) {
            int sl = j * 8 + st;
            int   ss = __shfl(s, sl, 32);   // 0 (safe) when sl >= m
            float vv = __shfl(v, sl, 32);   // 0 when sl >= m
            int4 rw = hin4[(size_t)ss * 4 + c4];
            float2 f0 = __half22float2(*reinterpret_cast<__half2*>(&rw.x));
            float2 f1 = __half22float2(*reinterpret_cast<__half2*>(&rw.y));
            float2 f2 = __half22float2(*reinterpret_cast<__half2*>(&rw.z));
            float2 f3 = __half22float2(*reinterpret_cast<__half2*>(&rw.w));
            agg[0] = fmaf(vv, f0.x, agg[0]); agg[1] = fmaf(vv, f0.y, agg[1]);
            agg[2] = fmaf(vv, f1.x, agg[2]); agg[3] = fmaf(vv, f1.y, agg[3]);
            agg[4] = fmaf(vv, f2.x, agg[4]); agg[5] = fmaf(vv, f2.y, agg[5]);
            agg[6] = fmaf(vv, f3.x, agg[6]); agg[7] = fmaf(vv, f3.y, agg[7]);
        }
    }
    #pragma unroll
    for (int i = 0; i < 8; ++i) {
        agg[i] += __shfl_xor(agg[i], 4, 32);
        agg[i] += __shfl_xor(agg[i], 8, 32);
        agg[i] += __shfl_xor(agg[i], 16, 32);
    }
    if (lane < 4) {
        __half2 ha = __floats2half2_rn(agg[0], agg[1]);
        __half2 hb = __floats2half2_rn(agg[2], agg[3]);
        __half2 hc = __floats2half2_rn(agg[4], agg[5]);
        __half2 hd = __floats2half2_rn(agg[6], agg[7]);
        int4 pkv;
        pkv.x = *(int*)&ha; pkv.y = *(int*)&hb;
        pkv.z = *(int*)&hc; pkv.w = *(int*)&hd;
        ((int4*)hout)[(size_t)n * 4 + lane] = pkv;
    }
}

// --- MFMA epilogue: o = b + [f0|h1|h2|h3] @ [W0;W1;W2;W3]; relu -> fp16 f0 / fp32 out.
//     One wave per 16-node tile (grid-stride). W split hi+lo fp16 (W err ~2^-21). ---
__global__ __launch_bounds__(256) void epilogue_kernel(
    const ushort* __restrict__ f0, const ushort* __restrict__ h1,
    const ushort* __restrict__ h2, const ushort* __restrict__ h3,
    ushort* __restrict__ f0out, float* __restrict__ outf,
    const float* __restrict__ Wl, const float* __restrict__ bias, int last) {
    int tid = threadIdx.x;
    int lane = tid & 63;
    int wv = tid >> 6;
    int m = lane & 15;
    int kq = lane >> 4;   // 0..3
    half8 Bhi[4][2], Blo[4][2];
    #pragma unroll
    for (int c = 0; c < 4; ++c) {
        #pragma unroll
        for (int h = 0; h < 2; ++h) {
            #pragma unroll
            for (int j = 0; j < 8; ++j) {
                float w = Wl[c * 1024 + (kq * 8 + j) * 32 + h * 16 + m];
                _Float16 hi = (_Float16)w;
                Bhi[c][h][j] = hi;
                Blo[c][h][j] = (_Float16)(w - (float)hi);
            }
        }
    }
    float b0 = bias[m], b1 = bias[16 + m];
    const half8* A0 = (const half8*)f0;
    const half8* A1 = (const half8*)h1;
    const half8* A2 = (const half8*)h2;
    const half8* A3 = (const half8*)h3;
    int wgid = blockIdx.x * 4 + wv;
    for (int t = wgid; t < NTILE; t += 391 * 4) {
        int n0 = t * 16;
        int ai = (n0 + m) * 4 + kq;
        f32x4 acc0 = {0.f, 0.f, 0.f, 0.f};
        f32x4 acc1 = {0.f, 0.f, 0.f, 0.f};
        half8 a;
        a = A0[ai];
        acc0 = __builtin_amdgcn_mfma_f32_16x16x32_f16(a, Bhi[0][0], acc0, 0, 0, 0);
        acc0 = __builtin_amdgcn_mfma_f32_16x16x32_f16(a, Blo[0][0], acc0, 0, 0, 0);
        acc1 = __builtin_amdgcn_mfma_f32_16x16x32_f16(a, Bhi[0][1], acc1, 0, 0, 0);
        acc1 = __builtin_amdgcn_mfma_f32_16x16x32_f16(a, Blo[0][1], acc1, 0, 0, 0);
        a = A1[ai];
        acc0 = __builtin_amdgcn_mfma_f32_16x16x32_f16(a, Bhi[1][0], acc0, 0, 0, 0);
        acc0 = __builtin_amdgcn_mfma_f32_16x16x32_f16(a, Blo[1][0], acc0, 0, 0, 0);
        acc1 = __builtin_amdgcn_mfma_f32_16x16x32_f16(a, Bhi[1][1], acc1, 0, 0, 0);
        acc1 = __builtin_amdgcn_mfma_f32_16x16x32_f16(a, Blo[1][1], acc1, 0, 0, 0);
        a = A2[ai];
        acc0 = __builtin_amdgcn_mfma_f32_16x16x32_f16(a, Bhi[2][0], acc0, 0, 0, 0);
        acc0 = __builtin_amdgcn_mfma_f32_16x16x32_f16(a, Blo[2][0], acc0, 0, 0, 0);
        acc1 = __builtin_amdgcn_mfma_f32_16x16x32_f16(a, Bhi[2][1], acc1, 0, 0, 0);
        acc1 = __builtin_amdgcn_mfma_f32_16x16x32_f16(a, Blo[2][1], acc1, 0, 0, 0);
        a = A3[ai];
        acc0 = __builtin_amdgcn_mfma_f32_16x16x32_f16(a, Bhi[3][0], acc0, 0, 0, 0);
        acc0 = __builtin_amdgcn_mfma_f32_16x16x32_f16(a, Blo[3][0], acc0, 0, 0, 0);
        acc1 = __builtin_amdgcn_mfma_f32_16x16x32_f16(a, Bhi[3][1], acc1, 0, 0, 0);
        acc1 = __builtin_amdgcn_mfma_f32_16x16x32_f16(a, Blo[3][1], acc1, 0, 0, 0);
        #pragma unroll
        for (int r = 0; r < 4; ++r) {
            int rowi = n0 + kq * 4 + r;
            float v0 = fmaxf(acc0[r] + b0, 0.f);
            float v1 = fmaxf(acc1[r] + b1, 0.f);
            if (last) {
                outf[rowi * DD + m] = v0;
                outf[rowi * DD + 16 + m] = v1;
            } else {
                ((__half*)f0out)[rowi * DD + m] = __float2half(v0);
                ((__half*)f0out)[rowi * DD + 16 + m] = __float2half(v1);
            }
        }
    }
}

extern "C" void kernel_launch(void* const* d_in, const int* in_sizes, int n_in,
                              void* d_out, int out_size, void* d_ws, size_t ws_size,
                              hipStream_t stream) {
    const float* x  = (const float*)d_in[0];
    const int*   ei = (const int*)d_in[1];
    const float* ew = (const float*)d_in[2];
    const float* W  = (const float*)d_in[3];
    const float* b  = (const float*)d_in[4];
    float* out = (float*)d_out;

    const int* row = ei;        // source
    const int* col = ei + NE;   // target

    // ws layout (bytes) — IDENTICAL offsets to the proven R6 layout; epair now uses
    // only the first half of its 12.8M region (4B packed):
    //   pk8/h3 6.4M | epair 12.8M(region) | rank/h1 6.4M | f0 6.4M | h2 6.4M |
    //   off8 3.2M | cnt | dis | ptr | bsum     (~42.8 MB total)
    char* base = (char*)d_ws;
    unsigned long long* pk8 = (unsigned long long*)base;
    ushort*   h3    = (ushort*)base;                      // overlaid: pk8 dead after reduce
    unsigned* epair = (unsigned*)(base + 6400000);
    int*      rank  = (int*)(base + 6400000 + 12800000);  // overlaid with h1
    ushort*   h1    = (ushort*)rank;                      // first written after fill
    ushort*   f0    = (ushort*)(base + 25600000);
    ushort*   h2    = (ushort*)(base + 32000000);
    int*      off8  = (int*)(base + 38400000);
    int*      cnt   = off8 + (size_t)NX * NN;
    float*    dis   = (float*)(cnt + NN);
    int*      ptr   = (int*)(dis + NN);
    int*      bsum  = ptr + NN + 1;

    // ---- build CSR-by-target + norms ----
    hipMemsetAsync(pk8, 0, (size_t)NX * NN * sizeof(unsigned long long), stream);
    cvt_kernel<<<(NN * DD + 255) / 256, 256, 0, stream>>>(x, (__half*)f0);
    hist_rank_kernel<<<(NE + 255) / 256, 256, 0, stream>>>(col, ew, pk8, rank);
    reduce_kernel<<<NB, 256, 0, stream>>>(pk8, cnt, dis, off8);
    scan_block_kernel<<<NB, 256, 0, stream>>>(cnt, ptr, bsum);
    scan_top_kernel<<<1, 512, 0, stream>>>(bsum, ptr);
    scan_add_kernel<<<NB, 256, 0, stream>>>(ptr, bsum);
    fill_kernel<<<(NE + 255) / 256, 256, 0, stream>>>(row, col, ew, rank, dis, ptr, off8, epair);

    // ---- layers: f0 = layer input (fp16, updated in place by epilogue) ----
    const int grid = NN / 8;
    for (int l = 0; l < NL; ++l) {
        const float* Wl = W + (size_t)l * (NK + 1) * DD * DD;
        const float* bl = b + (size_t)l * DD;
        int lastl = (l == NL - 1);
        gather_kernel<<<grid, 256, 0, stream>>>(f0, h1, ptr, epair);   // k=1
        gather_kernel<<<grid, 256, 0, stream>>>(h1, h2, ptr, epair);   // k=2
        gather_kernel<<<grid, 256, 0, stream>>>(h2, h3, ptr, epair);   // k=3
        epilogue_kernel<<<391, 256, 0, stream>>>(f0, h1, h2, h3, f0, out,
                                                 Wl, bl, lastl);
    }
}

// Round 9
// 441.698 us; speedup vs baseline: 1.5783x; 1.0415x over previous
//
#include <hip/hip_runtime.h>
#include <hip/hip_fp16.h>

#define NN 100000
#define NE 1600000
#define DD 32
#define NL 3
#define NK 3
#define NB ((NN + 255) / 256)   // 391 scan blocks
#define NTB (NN / 16)           // 6250 fused-kernel blocks

typedef _Float16 half8 __attribute__((ext_vector_type(8)));
typedef float f32x4 __attribute__((ext_vector_type(4)));

// --- packed histogram, single copy: count [48..], fp(2^-40) wsum [0..48).
//     Returned old count = this edge's rank within its target's list. ---
__global__ void hist_rank_kernel(const int* __restrict__ col, const float* __restrict__ w,
                                 unsigned long long* __restrict__ pk, int* __restrict__ rank) {
    int e = blockIdx.x * blockDim.x + threadIdx.x;
    if (e < NE) {
        int c = col[e];
        unsigned long long enc = (1ull << 48) |
            (unsigned long long)((double)w[e] * 1099511627776.0);  // w * 2^40
        unsigned long long old = atomicAdd(&pk[c], enc);
        rank[e] = (int)(old >> 48);
    }
}

// --- per-block scan of counts (from pk) -> ptr partial + bsum; also dis ---
__global__ void scan_block_kernel(const unsigned long long* __restrict__ pk,
                                  float* __restrict__ dis,
                                  int* __restrict__ ptr, int* __restrict__ bsum) {
    __shared__ int s[256];
    int t = threadIdx.x;
    int i = blockIdx.x * 256 + t;
    unsigned long long p = (i < NN) ? pk[i] : 0ull;
    int v = (int)(p >> 48);
    s[t] = v;
    __syncthreads();
    for (int off = 1; off < 256; off <<= 1) {
        int add = (t >= off) ? s[t - off] : 0;
        __syncthreads();
        s[t] += add;
        __syncthreads();
    }
    if (i < NN) {
        ptr[i] = s[t] - v;
        float deg = (float)((double)(p & 0xFFFFFFFFFFFFull) * (1.0 / 1099511627776.0));
        dis[i] = deg > 0.f ? rsqrtf(deg) : 0.f;
    }
    if (t == 255) bsum[blockIdx.x] = s[255];
}

__global__ void scan_top_kernel(int* __restrict__ bsum, int* __restrict__ ptr) {
    __shared__ int s[512];
    int t = threadIdx.x;
    int v = (t < NB) ? bsum[t] : 0;
    s[t] = v;
    __syncthreads();
    for (int off = 1; off < 512; off <<= 1) {
        int add = (t >= off) ? s[t - off] : 0;
        __syncthreads();
        s[t] += add;
        __syncthreads();
    }
    if (t < NB) bsum[t] = s[t] - v;
    if (t == 0) ptr[NN] = NE;
}

// --- add block offsets; emit packed (ptr, dis) for fill's single random read ---
__global__ void scan_add_kernel(int* __restrict__ ptr, const int* __restrict__ bsum,
                                const float* __restrict__ dis, int2* __restrict__ pc) {
    int i = blockIdx.x * 256 + threadIdx.x;
    if (i < NN) {
        int pf = ptr[i] + bsum[i >> 8];
        ptr[i] = pf;
        pc[i] = make_int2(pf, __float_as_int(dis[i]));
    }
}

// --- fill CSR (no atomics): epair = (fp16_bits(norm) << 17) | src ---
__global__ void fill_kernel(const int* __restrict__ row, const int* __restrict__ col,
                            const float* __restrict__ w, const int* __restrict__ rank,
                            const float* __restrict__ dis, const int2* __restrict__ pc,
                            unsigned* __restrict__ epair) {
    int e = blockIdx.x * blockDim.x + threadIdx.x;
    if (e < NE) {
        int r = row[e], c = col[e];
        int2 P = pc[c];
        float nv = dis[r] * w[e] * __int_as_float(P.y);
        unsigned hb = (unsigned)__half_as_ushort(__float2half(nv));
        epair[P.x + rank[e]] = (hb << 17) | (unsigned)r;
    }
}

__global__ void cvt_kernel(const float* __restrict__ x, __half* __restrict__ xh) {
    int i = blockIdx.x * blockDim.x + threadIdx.x;
    if (i < NN * DD) xh[i] = __float2half(x[i]);
}

// --- pre-pack B fragments (hi/lo fp16 split, lane layout) for all layers ---
__global__ void prep_kernel(const float* __restrict__ W, half8* __restrict__ Bpk) {
    int l = blockIdx.x;
    int t = threadIdx.x;           // lane 0..63
    int m = t & 15, kq = t >> 4;
    for (int c = 0; c < 4; ++c) {
        for (int h = 0; h < 2; ++h) {
            half8 hi, lo;
            for (int j = 0; j < 8; ++j) {
                float w = W[(size_t)((l * 4 + c) * DD + kq * 8 + j) * DD + h * 16 + m];
                _Float16 wh = (_Float16)w;
                hi[j] = wh;
                lo[j] = (_Float16)(w - (float)wh);
            }
            Bpk[(size_t)(((l * 4 + c) * 2 + h) * 2 + 0) * 64 + t] = hi;
            Bpk[(size_t)(((l * 4 + c) * 2 + h) * 2 + 1) * 64 + t] = lo;
        }
    }
}

// ---- shared gather body: agg[8] per lane, dims (lane&3)*8+i, replicated over streams ----
__device__ __forceinline__ void gather_body(const ushort* __restrict__ hin,
                                            const unsigned* __restrict__ epair,
                                            int p0, int p1, int lane, int st, int c4,
                                            float agg[8]) {
    const int4* hin4 = (const int4*)hin;
    for (int e0 = p0; e0 < p1; e0 += 32) {
        int m = p1 - e0;
        if (m > 32) m = 32;
        int s = 0;
        float v = 0.f;
        if (lane < m) {
            unsigned p = __builtin_nontemporal_load(epair + e0 + lane);
            s = (int)(p & 0x1FFFFu);
            v = __half2float(__ushort_as_half((unsigned short)(p >> 17)));
        }
        int nit = (m + 7) >> 3;
        #pragma unroll 2
        for (int j = 0; j < nit; ++j) {
            int sl = j * 8 + st;
            int   ss = __shfl(s, sl, 32);   // 0 (safe) when sl >= m
            float vv = __shfl(v, sl, 32);   // 0 when sl >= m
            int4 rw = hin4[(size_t)ss * 4 + c4];
            float2 f0 = __half22float2(*reinterpret_cast<__half2*>(&rw.x));
            float2 f1 = __half22float2(*reinterpret_cast<__half2*>(&rw.y));
            float2 f2 = __half22float2(*reinterpret_cast<__half2*>(&rw.z));
            float2 f3 = __half22float2(*reinterpret_cast<__half2*>(&rw.w));
            agg[0] = fmaf(vv, f0.x, agg[0]); agg[1] = fmaf(vv, f0.y, agg[1]);
            agg[2] = fmaf(vv, f1.x, agg[2]); agg[3] = fmaf(vv, f1.y, agg[3]);
            agg[4] = fmaf(vv, f2.x, agg[4]); agg[5] = fmaf(vv, f2.y, agg[5]);
            agg[6] = fmaf(vv, f3.x, agg[6]); agg[7] = fmaf(vv, f3.y, agg[7]);
        }
    }
    #pragma unroll
    for (int i = 0; i < 8; ++i) {
        agg[i] += __shfl_xor(agg[i], 4, 32);
        agg[i] += __shfl_xor(agg[i], 8, 32);
        agg[i] += __shfl_xor(agg[i], 16, 32);
    }
}

// --- pure hop: hout[n] = sum norm*hin[src], fp16 in/out ---
__global__ __launch_bounds__(256) void gather_kernel(
    const ushort* __restrict__ hin, ushort* __restrict__ hout,
    const int* __restrict__ ptr, const unsigned* __restrict__ epair) {
    int tid = threadIdx.x;
    int lane = tid & 31;
    int st = lane >> 2, c4 = lane & 3;
    int n = blockIdx.x * 8 + (tid >> 5);
    if (n >= NN) return;
    int p0 = ptr[n], p1 = ptr[n + 1];
    float agg[8] = {0.f, 0.f, 0.f, 0.f, 0.f, 0.f, 0.f, 0.f};
    gather_body(hin, epair, p0, p1, lane, st, c4, agg);
    if (lane < 4) {
        __half2 ha = __floats2half2_rn(agg[0], agg[1]);
        __half2 hb = __floats2half2_rn(agg[2], agg[3]);
        __half2 hc = __floats2half2_rn(agg[4], agg[5]);
        __half2 hd = __floats2half2_rn(agg[6], agg[7]);
        int4 pkv;
        pkv.x = *(int*)&ha; pkv.y = *(int*)&hb;
        pkv.z = *(int*)&hc; pkv.w = *(int*)&hd;
        ((int4*)hout)[(size_t)n * 4 + lane] = pkv;
    }
}

// --- fused k=3 gather + MFMA epilogue. 512 threads = 16 nodes (gather, 32 lanes/node);
//     agg -> 1KB LDS tile -> wave 0 does o = b + [f0|h1|h2|h3]@W, relu, store.
//     h3 never hits global. In-place f0 update is safe: gather input is h2 only. ---
__global__ __launch_bounds__(512) void k3ep_kernel(
    const ushort* __restrict__ f0, const ushort* __restrict__ h1,
    const ushort* __restrict__ h2,
    ushort* __restrict__ f0out, float* __restrict__ outf,
    const int* __restrict__ ptr, const unsigned* __restrict__ epair,
    const half8* __restrict__ Bp, const float* __restrict__ bias, int last) {
    __shared__ __half ldsH[16 * DD];
    int tid = threadIdx.x;
    int lane = tid & 31;
    int st = lane >> 2, c4 = lane & 3;
    int nloc = tid >> 5;                 // 0..15
    int n0 = blockIdx.x * 16;
    int n = n0 + nloc;                   // NN = 6250*16 exactly, no guard needed
    int p0 = ptr[n], p1 = ptr[n + 1];
    float agg[8] = {0.f, 0.f, 0.f, 0.f, 0.f, 0.f, 0.f, 0.f};
    gather_body(h2, epair, p0, p1, lane, st, c4, agg);
    if (lane < 4) {
        __half2 ha = __floats2half2_rn(agg[0], agg[1]);
        __half2 hb = __floats2half2_rn(agg[2], agg[3]);
        __half2 hc = __floats2half2_rn(agg[4], agg[5]);
        __half2 hd = __floats2half2_rn(agg[6], agg[7]);
        int4 pkv;
        pkv.x = *(int*)&ha; pkv.y = *(int*)&hb;
        pkv.z = *(int*)&hc; pkv.w = *(int*)&hd;
        *(int4*)&ldsH[nloc * DD + c4 * 8] = pkv;
    }
    __syncthreads();
    if (tid < 64) {
        int m = tid & 15, kq = tid >> 4;
        int ai = (n0 + m) * 4 + kq;
        const half8* A0 = (const half8*)f0;
        const half8* A1 = (const half8*)h1;
        const half8* A2 = (const half8*)h2;
        f32x4 acc0 = {0.f, 0.f, 0.f, 0.f};
        f32x4 acc1 = {0.f, 0.f, 0.f, 0.f};
        half8 a;
        a = A0[ai];
        acc0 = __builtin_amdgcn_mfma_f32_16x16x32_f16(a, Bp[0 * 64 + tid], acc0, 0, 0, 0);
        acc0 = __builtin_amdgcn_mfma_f32_16x16x32_f16(a, Bp[1 * 64 + tid], acc0, 0, 0, 0);
        acc1 = __builtin_amdgcn_mfma_f32_16x16x32_f16(a, Bp[2 * 64 + tid], acc1, 0, 0, 0);
        acc1 = __builtin_amdgcn_mfma_f32_16x16x32_f16(a, Bp[3 * 64 + tid], acc1, 0, 0, 0);
        a = A1[ai];
        acc0 = __builtin_amdgcn_mfma_f32_16x16x32_f16(a, Bp[4 * 64 + tid], acc0, 0, 0, 0);
        acc0 = __builtin_amdgcn_mfma_f32_16x16x32_f16(a, Bp[5 * 64 + tid], acc0, 0, 0, 0);
        acc1 = __builtin_amdgcn_mfma_f32_16x16x32_f16(a, Bp[6 * 64 + tid], acc1, 0, 0, 0);
        acc1 = __builtin_amdgcn_mfma_f32_16x16x32_f16(a, Bp[7 * 64 + tid], acc1, 0, 0, 0);
        a = A2[ai];
        acc0 = __builtin_amdgcn_mfma_f32_16x16x32_f16(a, Bp[8 * 64 + tid], acc0, 0, 0, 0);
        acc0 = __builtin_amdgcn_mfma_f32_16x16x32_f16(a, Bp[9 * 64 + tid], acc0, 0, 0, 0);
        acc1 = __builtin_amdgcn_mfma_f32_16x16x32_f16(a, Bp[10 * 64 + tid], acc1, 0, 0, 0);
        acc1 = __builtin_amdgcn_mfma_f32_16x16x32_f16(a, Bp[11 * 64 + tid], acc1, 0, 0, 0);
        a = *(const half8*)&ldsH[m * DD + kq * 8];
        acc0 = __builtin_amdgcn_mfma_f32_16x16x32_f16(a, Bp[12 * 64 + tid], acc0, 0, 0, 0);
        acc0 = __builtin_amdgcn_mfma_f32_16x16x32_f16(a, Bp[13 * 64 + tid], acc0, 0, 0, 0);
        acc1 = __builtin_amdgcn_mfma_f32_16x16x32_f16(a, Bp[14 * 64 + tid], acc1, 0, 0, 0);
        acc1 = __builtin_amdgcn_mfma_f32_16x16x32_f16(a, Bp[15 * 64 + tid], acc1, 0, 0, 0);
        float b0 = bias[m], b1 = bias[16 + m];
        #pragma unroll
        for (int r = 0; r < 4; ++r) {
            int rowi = n0 + kq * 4 + r;
            float v0 = fmaxf(acc0[r] + b0, 0.f);
            float v1 = fmaxf(acc1[r] + b1, 0.f);
            if (last) {
                outf[rowi * DD + m] = v0;
                outf[rowi * DD + 16 + m] = v1;
            } else {
                ((__half*)f0out)[rowi * DD + m] = __float2half(v0);
                ((__half*)f0out)[rowi * DD + 16 + m] = __float2half(v1);
            }
        }
    }
}

extern "C" void kernel_launch(void* const* d_in, const int* in_sizes, int n_in,
                              void* d_out, int out_size, void* d_ws, size_t ws_size,
                              hipStream_t stream) {
    const float* x  = (const float*)d_in[0];
    const int*   ei = (const int*)d_in[1];
    const float* ew = (const float*)d_in[2];
    const float* W  = (const float*)d_in[3];
    const float* b  = (const float*)d_in[4];
    float* out = (float*)d_out;

    const int* row = ei;        // source
    const int* col = ei + NE;   // target

    // ws layout (bytes), ~34.5 MB total (prior rounds proved >=42.8 MB available):
    // pk 0.8M | epair 6.4M | h1 6.4M | h2 6.4M | f0 6.4M | rank 6.4M |
    // ptr 400016 | dis 400000 | pc 800000 | bsum 2048 | Bpk 49152
    char* base = (char*)d_ws;
    unsigned long long* pk = (unsigned long long*)base;
    unsigned* epair = (unsigned*)(base + 800000);
    ushort*   h1    = (ushort*)(base + 7200000);
    ushort*   h2    = (ushort*)(base + 13600000);
    ushort*   f0    = (ushort*)(base + 20000000);
    int*      rank  = (int*)(base + 26400000);
    int*      ptr   = (int*)(base + 32800000);
    float*    dis   = (float*)(base + 33200016);
    int2*     pc    = (int2*)(base + 33600016);
    int*      bsum  = (int*)(base + 34400016);
    half8*    Bpk   = (half8*)(base + 34402080);

    // ---- build CSR-by-target + norms ----
    hipMemsetAsync(pk, 0, NN * sizeof(unsigned long long), stream);
    cvt_kernel<<<(NN * DD + 255) / 256, 256, 0, stream>>>(x, (__half*)f0);
    hist_rank_kernel<<<(NE + 255) / 256, 256, 0, stream>>>(col, ew, pk, rank);
    scan_block_kernel<<<NB, 256, 0, stream>>>(pk, dis, ptr, bsum);
    scan_top_kernel<<<1, 512, 0, stream>>>(bsum, ptr);
    scan_add_kernel<<<NB, 256, 0, stream>>>(ptr, bsum, dis, pc);
    fill_kernel<<<(NE + 255) / 256, 256, 0, stream>>>(row, col, ew, rank, dis, pc, epair);
    prep_kernel<<<NL, 64, 0, stream>>>(W, Bpk);

    // ---- layers: f0 = layer input (fp16, updated in place by fused epilogue) ----
    const int grid = NN / 8;
    for (int l = 0; l < NL; ++l) {
        int lastl = (l == NL - 1);
        gather_kernel<<<grid, 256, 0, stream>>>(f0, h1, ptr, epair);   // k=1
        gather_kernel<<<grid, 256, 0, stream>>>(h1, h2, ptr, epair);   // k=2
        k3ep_kernel<<<NTB, 512, 0, stream>>>(f0, h1, h2, f0, out, ptr, epair,
                                             Bpk + (size_t)l * 1024,
                                             b + (size_t)l * DD, lastl);
    }
}